// Round 2
// baseline (325.709 us; speedup 1.0000x reference)
//
#include <hip/hip_runtime.h>
#include <hip/hip_cooperative_groups.h>

namespace cg = cooperative_groups;

#define CCH 128      // channels
#define WIN 128      // time window (exact: receptive field of last step = 122)
#define TLEN 2048
#define NBATCH 8
#define NATOMS 3584
#define NEG 0.2f

struct Params {
    const float *x, *embed_w, *posamp_w, *posamp_b, *reduce_w, *reduce_b;
    const float *dil_w, *dil_b, *one_w, *one_b;
    const float *aw1, *ab1, *aw2, *ab2, *aw3, *ab3;
    const float *pw1, *pb1, *pw2, *pb2, *pw3, *pb3;
    float *buf0, *buf1, *h2buf;     // workspace
    float *out;
};

__device__ __forceinline__ float lrelu(float v) { return v >= 0.f ? v : NEG * v; }

// One cooperative kernel: setup -> 6 dilated residual layers -> heads.
// Grid: 128 blocks (8 batches x 16 col-groups) x 512 threads.
// Thread (c = tid&127, sl = tid>>7) owns channel c at columns {w0+sl, w0+sl+4}.
__global__ void __launch_bounds__(512, 1) fused(Params P)
{
    cg::grid_group grid = cg::this_grid();
    const int bid = blockIdx.x;            // 0..127
    const int b   = bid >> 4;
    const int wg  = bid & 15;
    const int w0  = wg * 8;
    const int tid = threadIdx.x;
    const int c   = tid & (CCH - 1);
    const int sl  = tid >> 7;              // 0..3

    __shared__ float cat[8][2 * CCH];      // setup concat
    __shared__ float cols[3][8][CCH];      // 3 taps x 8 columns
    __shared__ float ybuf[8][CCH];         // dilconv output
    __shared__ float hfA[CCH], h1A[CCH], h1P[CCH], h2P[CCH];
    __shared__ float hs[CCH];              // final-phase h2 stage

    // ---------------- setup: h0 = reduce([embed | posamp]) ----------------
    {
        const float* xb = P.x + b * 4 * TLEN;
        const float pwa = P.posamp_w[2 * c];
        const float pwb = P.posamp_w[2 * c + 1];
        const float pbb = P.posamp_b[c];
        for (int q = 0; q < 2; ++q) {
            int p = sl + q * 4;
            int t = TLEN - WIN + w0 + p;
            int idx = (int)xb[t];                      // atom id, exact in f32
            float pos = xb[TLEN + t];
            float amp = xb[2 * TLEN + t];
            cat[p][c]       = P.embed_w[idx * CCH + c];
            cat[p][CCH + c] = pwa * pos + pwb * amp + pbb;
        }
        __syncthreads();
        const float* rw = P.reduce_w + c * (2 * CCH);
        float a0 = P.reduce_b[c], a1 = a0;
        const float* s0 = &cat[sl][0];
        const float* s1 = &cat[sl + 4][0];
        #pragma unroll 4
        for (int j = 0; j < 2 * CCH; ++j) {
            float wv = rw[j];
            a0 += wv * s0[j];
            a1 += wv * s1[j];
        }
        P.buf0[(b * WIN + w0 + sl)     * CCH + c] = a0;
        P.buf0[(b * WIN + w0 + sl + 4) * CCH + c] = a1;
    }
    grid.sync();

    // ---------------- 6 residual dilated blocks ----------------
    const int dils[6] = {1, 3, 9, 27, 81, 1};
    float* bufs[2] = {P.buf0, P.buf1};
    int cur = 0;

    for (int l = 0; l < 6; ++l) {
        const int d = dils[l];
        const float* Wd  = P.dil_w + (size_t)l * CCH * CCH * 3;
        const float* bd  = P.dil_b + (size_t)l * CCH;
        const float* Wo  = P.one_w + (size_t)l * CCH * CCH;
        const float* bo  = P.one_b + (size_t)l * CCH;
        const float* hin = bufs[cur];
        float* hout      = bufs[cur ^ 1];

        // stage 24 columns (3 taps x 8 cols), zero-fill outside window
        const float* hb = hin + b * WIN * CCH;
        for (int v = tid; v < 768; v += 512) {
            int tap = v >> 8, rem = v & 255, col = rem >> 5, f4 = rem & 31;
            int wp = w0 + col + (tap - 1) * d;
            float4 val = make_float4(0.f, 0.f, 0.f, 0.f);
            if (wp >= 0 && wp < WIN)
                val = *(const float4*)(hb + wp * CCH + f4 * 4);
            *(float4*)(&cols[tap][col][f4 * 4]) = val;
        }
        __syncthreads();

        // dilated k=3 conv, channel c, 2 time slots
        const float* Wr = Wd + c * CCH * 3;
        const float* m0 = &cols[0][sl][0];
        const float* c0 = &cols[1][sl][0];
        const float* p0 = &cols[2][sl][0];
        const float* m1 = &cols[0][sl + 4][0];
        const float* c1 = &cols[1][sl + 4][0];
        const float* p1 = &cols[2][sl + 4][0];
        float a0 = 0.f, a1 = 0.f;
        #pragma unroll 4
        for (int i = 0; i < CCH; ++i) {
            float wv0 = Wr[3 * i], wv1 = Wr[3 * i + 1], wv2 = Wr[3 * i + 2];
            a0 += wv0 * m0[i] + wv1 * c0[i] + wv2 * p0[i];
            a1 += wv0 * m1[i] + wv1 * c1[i] + wv2 * p1[i];
        }
        const float db = bd[c];
        ybuf[sl][c]     = a0 + db;
        ybuf[sl + 4][c] = a1 + db;
        __syncthreads();

        // 1x1 conv + residual + lrelu
        const float* Or = Wo + c * CCH;
        const float* y0 = &ybuf[sl][0];
        const float* y1 = &ybuf[sl + 4][0];
        float z0 = 0.f, z1 = 0.f;
        #pragma unroll 4
        for (int k = 0; k < CCH; ++k) {
            float wv = Or[k];
            z0 += wv * y0[k];
            z1 += wv * y1[k];
        }
        const float ob = bo[c];
        float r0 = lrelu(z0 + ob + c0[c]);
        float r1 = lrelu(z1 + ob + c1[c]);
        float* outp = hout + (b * WIN + w0) * CCH;
        outp[sl * CCH + c]       = r0;
        outp[(sl + 4) * CCH + c] = r1;
        cur ^= 1;

        // ---- tail of layer 6: wg==15 block holds column 127 -> hidden MLPs ----
        if (l == 5 && wg == 15) {
            if (sl == 3) hfA[c] = r1;          // column w0+7 == 127
            __syncthreads();
            if (sl < 2) {                       // sl==0: atom stack, sl==1: pa stack
                const float* w1 = sl ? P.pw1 : P.aw1;
                const float* b1 = sl ? P.pb1 : P.ab1;
                float s = b1[c];
                const float* r = w1 + c * CCH;
                #pragma unroll 4
                for (int k = 0; k < CCH; ++k) s += r[k] * hfA[k];
                (sl ? h1P : h1A)[c] = lrelu(s);
            }
            __syncthreads();
            if (sl < 2) {
                const float* w2 = sl ? P.pw2 : P.aw2;
                const float* b2 = sl ? P.pb2 : P.ab2;
                const float* hsrc = sl ? h1P : h1A;
                float s = b2[c];
                const float* r = w2 + c * CCH;
                #pragma unroll 4
                for (int k = 0; k < CCH; ++k) s += r[k] * hsrc[k];
                s = lrelu(s);
                if (sl == 0) P.h2buf[b * CCH + c] = s;   // atom h2 -> global
                else         h2P[c] = s;
            }
            __syncthreads();
            if (sl == 1 && c < 2) {             // pa head: 2 outputs per batch
                float s = P.pb3[c];
                const float* r = P.pw3 + c * CCH;
                #pragma unroll 4
                for (int k = 0; k < CCH; ++k) s += r[k] * h2P[k];
                P.out[NBATCH * NATOMS + b * 2 + c] = s;
            }
        }
        grid.sync();
    }

    // ---------------- final atom projection: 8 x 3584 rows ----------------
    if (bid < 56) {
        const int fb  = bid / 7;                // batch
        const int fj  = bid - fb * 7;
        const int row = fj * 512 + tid;         // 0..3583
        if (tid < CCH) hs[tid] = P.h2buf[fb * CCH + tid];
        __syncthreads();
        float s = P.ab3[row];
        const float4* r = (const float4*)(P.aw3 + (size_t)row * CCH);
        #pragma unroll 8
        for (int k = 0; k < CCH / 4; ++k) {
            float4 w4 = r[k];
            s += w4.x * hs[4 * k] + w4.y * hs[4 * k + 1]
               + w4.z * hs[4 * k + 2] + w4.w * hs[4 * k + 3];
        }
        P.out[fb * NATOMS + row] = s;
    }
}

// ---------------------------------------------------------------------------
extern "C" void kernel_launch(void* const* d_in, const int* in_sizes, int n_in,
                              void* d_out, int out_size, void* d_ws, size_t ws_size,
                              hipStream_t stream)
{
    Params P;
    P.x        = (const float*)d_in[0];
    P.embed_w  = (const float*)d_in[1];
    P.posamp_w = (const float*)d_in[2];
    P.posamp_b = (const float*)d_in[3];
    P.reduce_w = (const float*)d_in[4];
    P.reduce_b = (const float*)d_in[5];
    P.dil_w    = (const float*)d_in[6];
    P.dil_b    = (const float*)d_in[7];
    P.one_w    = (const float*)d_in[8];
    P.one_b    = (const float*)d_in[9];
    P.aw1 = (const float*)d_in[10]; P.ab1 = (const float*)d_in[11];
    P.aw2 = (const float*)d_in[12]; P.ab2 = (const float*)d_in[13];
    P.aw3 = (const float*)d_in[14]; P.ab3 = (const float*)d_in[15];
    P.pw1 = (const float*)d_in[16]; P.pb1 = (const float*)d_in[17];
    P.pw2 = (const float*)d_in[18]; P.pb2 = (const float*)d_in[19];
    P.pw3 = (const float*)d_in[20]; P.pb3 = (const float*)d_in[21];

    float* ws = (float*)d_ws;
    P.buf0  = ws;                               // [8][128][128]
    P.buf1  = ws + NBATCH * WIN * CCH;          // [8][128][128]
    P.h2buf = ws + 2 * NBATCH * WIN * CCH;      // [8][128]
    P.out   = (float*)d_out;

    void* args[] = { &P };
    hipLaunchCooperativeKernel((void*)fused, dim3(128), dim3(512), args, 0, stream);
}

// Round 3
// 216.732 us; speedup vs baseline: 1.5028x; 1.5028x over previous
//
#include <hip/hip_runtime.h>

#define CCH 128      // channels
#define WIN 128      // time window (exact: receptive field of last step = 122)
#define TLEN 2048
#define NBATCH 8
#define NATOMS 3584
#define NEG 0.2f

__device__ __forceinline__ float lrelu(float v) { return v >= 0.f ? v : NEG * v; }

// ---------------------------------------------------------------------------
// Kernel A: h0[b][w][c] for the last WIN positions.
// grid (32, 8) x 512 threads. Thread (c = tid&127, sl = tid>>7) owns channel c
// of column w0+sl (4 columns per block).
// ---------------------------------------------------------------------------
__global__ void __launch_bounds__(512) k_setup(
        const float* __restrict__ x,
        const float* __restrict__ embed_w,
        const float* __restrict__ posamp_w,
        const float* __restrict__ posamp_b,
        const float* __restrict__ reduce_w,
        const float* __restrict__ reduce_b,
        float* __restrict__ h0)
{
    const int b   = blockIdx.y;
    const int w0  = blockIdx.x * 4;
    const int tid = threadIdx.x;
    const int c   = tid & (CCH - 1);
    const int sl  = tid >> 7;              // 0..3

    __shared__ float cat[4][2 * CCH];

    const float* xb = x + b * 4 * TLEN;
    {
        int t = TLEN - WIN + w0 + sl;
        int idx = (int)xb[t];              // atom id (exact int in f32)
        float pos = xb[TLEN + t];
        float amp = xb[2 * TLEN + t];
        cat[sl][c]       = embed_w[idx * CCH + c];
        cat[sl][CCH + c] = posamp_w[2 * c] * pos + posamp_w[2 * c + 1] * amp
                         + posamp_b[c];
    }
    __syncthreads();

    const float4* rw = (const float4*)(reduce_w + c * (2 * CCH));
    const float*  s  = &cat[sl][0];
    float acc = reduce_b[c];
    #pragma unroll 8
    for (int k = 0; k < 64; ++k) {
        float4 w4 = rw[k];
        acc += w4.x * s[4 * k] + w4.y * s[4 * k + 1]
             + w4.z * s[4 * k + 2] + w4.w * s[4 * k + 3];
    }
    h0[(b * WIN + w0 + sl) * CCH + c] = acc;
}

// ---------------------------------------------------------------------------
// Kernel B: one residual dilated block.
//   y = dilconv3(h) + dil_b ; z = one_w @ y + one_b ; h' = lrelu(z + h)
// grid (32, 8) x 512 threads; thread (c, sl) = channel c, column w0+sl.
// Weights read as per-thread float4 rows (L1/L2-hit); data via wave-uniform
// LDS broadcasts (sl is wave-uniform => conflict-free).
// Out-of-window columns zero (exact: left-edge contamination reaches w<=121).
// ---------------------------------------------------------------------------
__global__ void __launch_bounds__(512) k_layer(
        const float* __restrict__ hin,
        const float* __restrict__ Wd,   // [C][C][3] layer slice
        const float* __restrict__ bd,   // [C]
        const float* __restrict__ Wo,   // [C][C]
        const float* __restrict__ bo,   // [C]
        float* __restrict__ hout,
        int d)
{
    const int b   = blockIdx.y;
    const int w0  = blockIdx.x * 4;
    const int tid = threadIdx.x;
    const int c   = tid & (CCH - 1);
    const int sl  = tid >> 7;              // 0..3

    __shared__ float cols[3][4][CCH];      // taps -d,0,+d for 4 columns
    __shared__ float ybuf[4][CCH];

    // stage 12 columns (3 taps x 4 cols) as float4, zero-fill outside window
    const float* hb = hin + b * WIN * CCH;
    if (tid < 384) {
        int tap = tid >> 7;                // 0..2
        int rem = tid & 127;
        int col = rem >> 5;                // 0..3
        int f4  = rem & 31;                // 0..31
        int wp  = w0 + col + (tap - 1) * d;
        float4 val = make_float4(0.f, 0.f, 0.f, 0.f);
        if (wp >= 0 && wp < WIN)
            val = *(const float4*)(hb + wp * CCH + f4 * 4);
        *(float4*)(&cols[tap][col][f4 * 4]) = val;
    }
    __syncthreads();

    // dilated k=3 conv: row c of Wd = 384 floats = 96 float4
    const float4* Wr = (const float4*)(Wd + c * (CCH * 3));
    const float* cm = &cols[0][sl][0];
    const float* cc = &cols[1][sl][0];
    const float* cp = &cols[2][sl][0];
    float acc = 0.f;
    #pragma unroll 4
    for (int i = 0; i < CCH; i += 4) {
        int j = (3 * i) >> 2;              // i%4==0 -> exact
        float4 wA = Wr[j], wB = Wr[j + 1], wC = Wr[j + 2];
        acc += wA.x * cm[i]     + wA.y * cc[i]     + wA.z * cp[i]     + wA.w * cm[i + 1];
        acc += wB.x * cc[i + 1] + wB.y * cp[i + 1] + wB.z * cm[i + 2] + wB.w * cc[i + 2];
        acc += wC.x * cp[i + 2] + wC.y * cm[i + 3] + wC.z * cc[i + 3] + wC.w * cp[i + 3];
    }
    ybuf[sl][c] = acc + bd[c];
    __syncthreads();

    // 1x1 conv + residual + lrelu
    const float4* Or = (const float4*)(Wo + c * CCH);
    const float* y = &ybuf[sl][0];
    float z = 0.f;
    #pragma unroll 8
    for (int k = 0; k < 32; ++k) {
        float4 w4 = Or[k];
        z += w4.x * y[4 * k] + w4.y * y[4 * k + 1]
           + w4.z * y[4 * k + 2] + w4.w * y[4 * k + 3];
    }
    hout[(b * WIN + w0 + sl) * CCH + c] = lrelu(z + bo[c] + cc[c]);
}

// ---------------------------------------------------------------------------
// Kernel C: output stacks on the last column only.
// grid (29, 8) x 128 threads. Blocks 0..27: atom logit rows; block 28: pa.
// ---------------------------------------------------------------------------
__global__ void __launch_bounds__(128) k_final(
        const float* __restrict__ hfin,
        const float* __restrict__ aw1, const float* __restrict__ ab1,
        const float* __restrict__ aw2, const float* __restrict__ ab2,
        const float* __restrict__ aw3, const float* __restrict__ ab3,
        const float* __restrict__ pw1, const float* __restrict__ pb1,
        const float* __restrict__ pw2, const float* __restrict__ pb2,
        const float* __restrict__ pw3, const float* __restrict__ pb3,
        float* __restrict__ out)
{
    const int b = blockIdx.y;
    const int j = blockIdx.x;
    const int c = threadIdx.x;

    __shared__ float hf[CCH], h1[CCH], h2[CCH];
    hf[c] = hfin[(b * WIN + (WIN - 1)) * CCH + c];
    __syncthreads();

    const bool is_pa = (j == 28);
    const float* w1 = is_pa ? pw1 : aw1;  const float* b1 = is_pa ? pb1 : ab1;
    const float* w2 = is_pa ? pw2 : aw2;  const float* b2 = is_pa ? pb2 : ab2;

    float s = b1[c];
    const float4* r1 = (const float4*)(w1 + c * CCH);
    #pragma unroll 8
    for (int k = 0; k < 32; ++k) {
        float4 w4 = r1[k];
        s += w4.x * hf[4 * k] + w4.y * hf[4 * k + 1]
           + w4.z * hf[4 * k + 2] + w4.w * hf[4 * k + 3];
    }
    h1[c] = lrelu(s);
    __syncthreads();

    s = b2[c];
    const float4* r2 = (const float4*)(w2 + c * CCH);
    #pragma unroll 8
    for (int k = 0; k < 32; ++k) {
        float4 w4 = r2[k];
        s += w4.x * h1[4 * k] + w4.y * h1[4 * k + 1]
           + w4.z * h1[4 * k + 2] + w4.w * h1[4 * k + 3];
    }
    h2[c] = lrelu(s);
    __syncthreads();

    if (!is_pa) {
        int ro = j * CCH + c;
        float s3 = ab3[ro];
        const float4* r3 = (const float4*)(aw3 + (size_t)ro * CCH);
        #pragma unroll 8
        for (int k = 0; k < 32; ++k) {
            float4 w4 = r3[k];
            s3 += w4.x * h2[4 * k] + w4.y * h2[4 * k + 1]
                + w4.z * h2[4 * k + 2] + w4.w * h2[4 * k + 3];
        }
        out[b * NATOMS + ro] = s3;
    } else if (c < 2) {
        float s3 = pb3[c];
        const float* r3 = pw3 + c * CCH;
        for (int k = 0; k < CCH; ++k) s3 += r3[k] * h2[k];
        out[NBATCH * NATOMS + b * 2 + c] = s3;
    }
}

// ---------------------------------------------------------------------------
extern "C" void kernel_launch(void* const* d_in, const int* in_sizes, int n_in,
                              void* d_out, int out_size, void* d_ws, size_t ws_size,
                              hipStream_t stream)
{
    const float* x        = (const float*)d_in[0];
    const float* embed_w  = (const float*)d_in[1];
    const float* posamp_w = (const float*)d_in[2];
    const float* posamp_b = (const float*)d_in[3];
    const float* reduce_w = (const float*)d_in[4];
    const float* reduce_b = (const float*)d_in[5];
    const float* dil_w    = (const float*)d_in[6];
    const float* dil_b    = (const float*)d_in[7];
    const float* one_w    = (const float*)d_in[8];
    const float* one_b    = (const float*)d_in[9];
    const float* aw1 = (const float*)d_in[10]; const float* ab1 = (const float*)d_in[11];
    const float* aw2 = (const float*)d_in[12]; const float* ab2 = (const float*)d_in[13];
    const float* aw3 = (const float*)d_in[14]; const float* ab3 = (const float*)d_in[15];
    const float* pw1 = (const float*)d_in[16]; const float* pb1 = (const float*)d_in[17];
    const float* pw2 = (const float*)d_in[18]; const float* pb2 = (const float*)d_in[19];
    const float* pw3 = (const float*)d_in[20]; const float* pb3 = (const float*)d_in[21];

    float* buf0 = (float*)d_ws;                       // [8][128][128] f32
    float* buf1 = buf0 + NBATCH * WIN * CCH;          // ping-pong

    k_setup<<<dim3(32, NBATCH), 512, 0, stream>>>(
        x, embed_w, posamp_w, posamp_b, reduce_w, reduce_b, buf0);

    const int dil[6] = {1, 3, 9, 27, 81, 1};
    float* bufs[2] = {buf0, buf1};
    int cur = 0;
    for (int l = 0; l < 6; ++l) {
        k_layer<<<dim3(32, NBATCH), 512, 0, stream>>>(
            bufs[cur],
            dil_w + (size_t)l * CCH * CCH * 3,
            dil_b + (size_t)l * CCH,
            one_w + (size_t)l * CCH * CCH,
            one_b + (size_t)l * CCH,
            bufs[cur ^ 1], dil[l]);
        cur ^= 1;
    }

    k_final<<<dim3(29, NBATCH), 128, 0, stream>>>(
        bufs[cur], aw1, ab1, aw2, ab2, aw3, ab3,
        pw1, pb1, pw2, pb2, pw3, pb3, (float*)d_out);
}